// Round 17
// baseline (156.260 us; speedup 1.0000x reference)
//
#include <hip/hip_runtime.h>
#include <math.h>

// s < S0  <=>  sqrtf(s) < 0.3f  (bit-exact equivalence for all f32 s >= 0).
// mid = (0.3f + pred(0.3f))/2; S0 = smallest float > mid^2 = 12079596 * 2^-27.
#define S0_THRESH 0x1.70A3D8p-4f
// Legacy screen constant (fallback kernel only), validated R9/R10/R15.
#define DOT_HI 0.954989f

#define NCELL 16          // 16^3 grid over [-1,1]^3, h = 0.125
#define CELL_STRIDE 32    // byte0 = count (0xFF = overflow), bytes1..31 = idx
#define LIST_BYTES (4096 * CELL_STRIDE)
// ||p - cell_center|| <= 0.3000001 (chord) + 0.0625*sqrt(3) (half-diag)
//                     = 0.4083 < 0.41;  0.41^2 = 0.1681 (double-math builder).
#define LIST_R2 0.1681

typedef float v2f __attribute__((ext_vector_type(2)));

// ws layout: [0, 2KB) float4 pairs pc[2j]=point, pc[2j+1]=color;
//            [2KB, 2KB+128KB) per-cell candidate lists.
__global__ void setup_points_kernel(const float* __restrict__ pointsSphere,
                                    const float* __restrict__ colors,
                                    float4* __restrict__ pc,
                                    int P, int ncolors) {
    int j = threadIdx.x;
    if (j >= P) return;
    double th = (double)pointsSphere[2 * j];
    double ph = (double)pointsSphere[2 * j + 1];
    float st = (float)sin(th);
    float ct = (float)cos(th);
    float sp = (float)sin(ph);
    float cp = (float)cos(ph);
    pc[2 * j] = make_float4(__fmul_rn(st, cp), __fmul_rn(st, sp), ct, 0.0f);
    const float* c = colors + 3 * (j % ncolors);
    pc[2 * j + 1] = make_float4(c[0], c[1], c[2], 0.0f);
}

// One thread per cell: ascending-j (np order) candidate list, double math.
__global__ void build_lists_kernel(const float4* __restrict__ pc,
                                   unsigned char* __restrict__ lists) {
    int cell = blockIdx.x * 256 + threadIdx.x;
    if (cell >= 4096) return;
    int cx = cell & 15, cy = (cell >> 4) & 15, cz = cell >> 8;
    double ccx = -1.0 + (cx + 0.5) * 0.125;
    double ccy = -1.0 + (cy + 0.5) * 0.125;
    double ccz = -1.0 + (cz + 0.5) * 0.125;
    unsigned char* L = lists + (size_t)cell * CELL_STRIDE;
    int n = 0;
    bool ovf = false;
    for (int j = 0; j < 64; ++j) {
        float4 p = pc[2 * j];  // uniform -> s_load
        double dx = (double)p.x - ccx;
        double dy = (double)p.y - ccy;
        double dz = (double)p.z - ccz;
        if (dx * dx + dy * dy + dz * dz <= LIST_R2) {
            if (n < 31) { L[1 + n] = (unsigned char)j; ++n; }
            else ovf = true;
        }
    }
    L[0] = ovf ? 0xFFu : (unsigned char)n;
}

__global__ __launch_bounds__(256, 8)
void blend_cell_kernel(const float* __restrict__ iso,
                       const float4* __restrict__ pc,
                       const unsigned char* __restrict__ lists,
                       float* __restrict__ out,
                       int nverts) {
    __shared__ float4 spc[128];
    if (threadIdx.x < 128) spc[threadIdx.x] = pc[threadIdx.x];
    __syncthreads();

    int i = blockIdx.x * 256 + threadIdx.x;
    if (i >= nverts) return;
    size_t base = 3 * (size_t)i;
    float vx = iso[base], vy = iso[base + 1], vz = iso[base + 2];

    // Cell id; trunc-toward-zero also clamps |v| eps-above-1 negatives to 0.
    int cxi = (int)((vx + 1.0f) * 8.0f); cxi = cxi > 15 ? 15 : cxi;
    int cyi = (int)((vy + 1.0f) * 8.0f); cyi = cyi > 15 ? 15 : cyi;
    int czi = (int)((vz + 1.0f) * 8.0f); czi = czi > 15 ? 15 : czi;
    int cell = (czi << 8) | (cyi << 4) | cxi;

    const unsigned char* L = lists + (size_t)cell * CELL_STRIDE;
    unsigned long long w = *(const unsigned long long*)L;  // count + idx[0..6]
    int count = (int)(w & 0xFFull);

    float cxc = 0.f, cyc = 0.f, czc = 0.f;

    auto resolve = [&](int j) {
        float4 p   = spc[2 * j];
        float4 col = spc[2 * j + 1];
        // Bit-exact np arithmetic (no contraction):
        float dx = __fsub_rn(p.x, vx);
        float dy = __fsub_rn(p.y, vy);
        float dz = __fsub_rn(p.z, vz);
        float s = __fadd_rn(__fadd_rn(__fmul_rn(dx, dx), __fmul_rn(dy, dy)),
                            __fmul_rn(dz, dz));
        if (s < S0_THRESH) {
            float d = __builtin_amdgcn_sqrtf(s);
            cxc = fmaf(-d, __fsub_rn(col.x, cxc), col.x);
            cyc = fmaf(-d, __fsub_rn(col.y, cyc), col.y);
            czc = fmaf(-d, __fsub_rn(col.z, czc), col.z);
        }
    };

    if (count == 0xFF) {
        // Overflowed cell (practically never): full ascending scan, same math.
        for (int j = 0; j < 64; ++j) resolve(j);
    } else {
        unsigned long long bits = w >> 8;
        for (int k = 0; k < count; ++k) {
            if (k == 7)       bits = *(const unsigned long long*)(L + 8);
            else if (k == 15) bits = *(const unsigned long long*)(L + 16);
            else if (k == 23) bits = *(const unsigned long long*)(L + 24);
            int j = (int)(bits & 0xFFull);
            bits >>= 8;
            resolve(j);  // ascending j == np scan order
        }
    }

    out[base] = cxc; out[base + 1] = cyc; out[base + 2] = czc;
}

// ---------------- Fallback (validated R15 kernel), used if ws too small ----
__global__ __launch_bounds__(256, 8)
void blend_mask_kernel(const float* __restrict__ iso,
                       const float4* __restrict__ pc,
                       float* __restrict__ out,
                       int nverts) {
    __shared__ float4 spc[128];
    if (threadIdx.x < 128) spc[threadIdx.x] = pc[threadIdx.x];
    __syncthreads();

    int t = blockIdx.x * 256 + threadIdx.x;
    int i0 = 2 * t;
    if (i0 >= nverts) return;
    bool pair = (i0 + 1) < nverts;
    size_t base = 3 * (size_t)i0;

    v2f vvx, vvy, vvz;
    if (pair) {
        float2 a0 = *(const float2*)(iso + base);
        float2 a1 = *(const float2*)(iso + base + 2);
        float2 a2 = *(const float2*)(iso + base + 4);
        vvx = (v2f){a0.x, a1.y};
        vvy = (v2f){a0.y, a2.x};
        vvz = (v2f){a1.x, a2.y};
    } else {
        vvx = (v2f){iso[base], 0.0f};
        vvy = (v2f){iso[base + 1], 0.0f};
        vvz = (v2f){iso[base + 2], -2.0f};
    }

    unsigned lo0 = 0, hi0 = 0, lo1 = 0, hi1 = 0;
#pragma unroll 8
    for (int j = 63; j >= 32; --j) {
        float4 p = pc[2 * j];
        v2f acc = (v2f){p.z, p.z} * vvz;
        acc = __builtin_elementwise_fma((v2f){p.y, p.y}, vvy, acc);
        acc = __builtin_elementwise_fma((v2f){p.x, p.x}, vvx, acc);
        hi0 = (hi0 << 1) | (acc.x > DOT_HI ? 1u : 0u);
        hi1 = (hi1 << 1) | (acc.y > DOT_HI ? 1u : 0u);
    }
#pragma unroll 8
    for (int j = 31; j >= 0; --j) {
        float4 p = pc[2 * j];
        v2f acc = (v2f){p.z, p.z} * vvz;
        acc = __builtin_elementwise_fma((v2f){p.y, p.y}, vvy, acc);
        acc = __builtin_elementwise_fma((v2f){p.x, p.x}, vvx, acc);
        lo0 = (lo0 << 1) | (acc.x > DOT_HI ? 1u : 0u);
        lo1 = (lo1 << 1) | (acc.y > DOT_HI ? 1u : 0u);
    }

    float cx0 = 0.f, cy0 = 0.f, cz0 = 0.f;
    float cx1 = 0.f, cy1 = 0.f, cz1 = 0.f;

    auto resolve32 = [&](unsigned m, int jbase, float vx, float vy, float vz,
                         float& cx, float& cy, float& cz) {
        while (m) {
            int j = jbase + __builtin_ctz(m);
            m &= m - 1;
            float4 p   = spc[2 * j];
            float4 col = spc[2 * j + 1];
            float dx = __fsub_rn(p.x, vx);
            float dy = __fsub_rn(p.y, vy);
            float dz = __fsub_rn(p.z, vz);
            float s = __fadd_rn(__fadd_rn(__fmul_rn(dx, dx), __fmul_rn(dy, dy)),
                                __fmul_rn(dz, dz));
            if (s < S0_THRESH) {
                float d = __builtin_amdgcn_sqrtf(s);
                cx = fmaf(-d, __fsub_rn(col.x, cx), col.x);
                cy = fmaf(-d, __fsub_rn(col.y, cy), col.y);
                cz = fmaf(-d, __fsub_rn(col.z, cz), col.z);
            }
        }
    };

    resolve32(lo0,  0, vvx.x, vvy.x, vvz.x, cx0, cy0, cz0);
    resolve32(hi0, 32, vvx.x, vvy.x, vvz.x, cx0, cy0, cz0);
    resolve32(lo1,  0, vvx.y, vvy.y, vvz.y, cx1, cy1, cz1);
    resolve32(hi1, 32, vvx.y, vvy.y, vvz.y, cx1, cy1, cz1);

    if (pair) {
        *(float2*)(out + base)     = make_float2(cx0, cy0);
        *(float2*)(out + base + 2) = make_float2(cz0, cx1);
        *(float2*)(out + base + 4) = make_float2(cy1, cz1);
    } else {
        out[base] = cx0; out[base + 1] = cy0; out[base + 2] = cz0;
    }
}

extern "C" void kernel_launch(void* const* d_in, const int* in_sizes, int n_in,
                              void* d_out, int out_size, void* d_ws, size_t ws_size,
                              hipStream_t stream) {
    const float* pointsSphere = (const float*)d_in[0];
    const float* colors       = (const float*)d_in[1];
    const float* iso          = (const float*)d_in[2];
    int P       = in_sizes[0] / 2;
    int ncolors = in_sizes[1] / 3;
    int nverts  = in_sizes[2] / 3;

    float4* pc = (float4*)d_ws;
    unsigned char* lists = (unsigned char*)d_ws + 2048;

    hipLaunchKernelGGL(setup_points_kernel, dim3(1), dim3(64), 0, stream,
                       pointsSphere, colors, pc, P, ncolors);

    if (ws_size >= 2048 + LIST_BYTES) {
        hipLaunchKernelGGL(build_lists_kernel, dim3(16), dim3(256), 0, stream,
                           pc, lists);
        int blocks = (nverts + 255) / 256;
        hipLaunchKernelGGL(blend_cell_kernel, dim3(blocks), dim3(256), 0, stream,
                           iso, pc, lists, (float*)d_out, nverts);
    } else {
        int nthreads = (nverts + 1) / 2;
        int blocks = (nthreads + 255) / 256;
        hipLaunchKernelGGL(blend_mask_kernel, dim3(blocks), dim3(256), 0, stream,
                           iso, pc, (float*)d_out, nverts);
    }
}